// Round 17
// baseline (527.531 us; speedup 1.0000x reference)
//
#include <hip/hip_runtime.h>
#include <math.h>

#define DM 256          // d_model
#define NS 64           // N state
#define SP 128          // spatial H == W

typedef __attribute__((ext_vector_type(8))) short bf16x8;
typedef __attribute__((ext_vector_type(4))) float f32x4;

__device__ __forceinline__ float gelu_f(float x) {
    float x3 = x * x * x;
    return 0.5f * x * (1.0f + tanhf(0.7978845608028654f * (x + 0.044715f * x3)));
}
__device__ __forceinline__ float sigmoid_f(float x) {
    return 1.0f / (1.0f + expf(-x));
}
__device__ __forceinline__ unsigned short f2bf(float f) {   // RNE f32->bf16
    unsigned u = __float_as_uint(f);
    u += 0x7fff + ((u >> 16) & 1);
    return (unsigned short)(u >> 16);
}
__device__ __forceinline__ float bf2f(unsigned short b) {
    return __uint_as_float(((unsigned)b) << 16);
}

// ---------------------------------------------------------------------------
// S4D tap generation -> Kd[la][d][q] fp32 (verified).
// ---------------------------------------------------------------------------
__global__ __launch_bounds__(128) void gen_k_kernel(
        const float* __restrict__ log_dt, const float* __restrict__ logA_re,
        const float* __restrict__ A_im,   const float* __restrict__ C_re,
        const float* __restrict__ C_im,   float* __restrict__ Kd) {
    int blk = blockIdx.x;
    int d  = blk & (DM - 1);
    int la = blk >> 8;
    int q  = threadIdx.x;
    __shared__ float s_cbr[NS], s_cbi[NS], s_dr[NS], s_di[NS];
    int pbase = (la * DM + d) * NS;
    float dt = expf(log_dt[la * DM + d]);
    if (q < NS) {
        int n = q;
        float ar = -expf(logA_re[pbase + n]);
        float ai = A_im[pbase + n];
        float dr = dt * ar, di = dt * ai;
        float er = expf(dr);
        float sn, cs;
        sincosf(di, &sn, &cs);
        float nr = er * cs - 1.0f, ni = er * sn;
        float inv = 1.0f / (ar * ar + ai * ai);
        float br = (nr * ar + ni * ai) * inv;
        float bi = (ni * ar - nr * ai) * inv;
        float cr = C_re[pbase + n], ci = C_im[pbase + n];
        s_cbr[n] = cr * br - ci * bi;
        s_cbi[n] = cr * bi + ci * br;
        s_dr[n] = dr;
        s_di[n] = di;
    }
    __syncthreads();
    float fq = (float)q;
    float acc = 0.0f;
    for (int n = 0; n < NS; ++n) {
        float pr = expf(s_dr[n] * fq);
        float sn, cs;
        sincosf(s_di[n] * fq, &sn, &cs);
        acc += s_cbr[n] * (pr * cs) - s_cbi[n] * (pr * sn);
    }
    Kd[((size_t)la * DM + d) * SP + q] = 2.0f * acc;
}

// ---------------------------------------------------------------------------
// W_out fp32 [l][k=256][n=512] -> Bt bf16 [l][n=512][k=256]
// ---------------------------------------------------------------------------
__global__ __launch_bounds__(256) void prep_b_kernel(
        const float* __restrict__ Wo, unsigned short* __restrict__ Bt) {
    int idx = blockIdx.x * 256 + threadIdx.x;
    int l = idx >> 17, rem = idx & 131071, n = rem >> 8, k = rem & 255;
    Bt[idx] = f2bf(Wo[(size_t)l * 131072 + k * 512 + n]);
}

// ---------------------------------------------------------------------------
// Encoder -> bf16 h_p (pos-major), packed pair stores.
// ---------------------------------------------------------------------------
__global__ __launch_bounds__(256) void encode_kernel(
        const float* __restrict__ x, const float* __restrict__ g,
        const float* __restrict__ W_enc, const float* __restrict__ b_enc,
        unsigned short* __restrict__ h) {
    int total = 4 * SP * SP * 128;   // channel pairs
    for (int idx = blockIdx.x * blockDim.x + threadIdx.x; idx < total;
         idx += gridDim.x * blockDim.x) {
        int c = (idx & 127) * 2;
        int pos = idx >> 7;
        float xv = x[pos], gv = g[pos];
        float v0 = xv * W_enc[c] + gv * W_enc[DM + c] + b_enc[c];
        float v1 = xv * W_enc[c + 1] + gv * W_enc[DM + c + 1] + b_enc[c + 1];
        unsigned o = (unsigned)f2bf(v0) | ((unsigned)f2bf(v1) << 16);
        *(unsigned*)(h + (size_t)pos * DM + c) = o;
    }
}

// ---------------------------------------------------------------------------
// Generic 64x64-tile ushort transpose: in [Ri rows][Ci] -> out [Ci][Ri].
// (verified r13-r16; FUSE path no longer needed.)
// ---------------------------------------------------------------------------
__global__ __launch_bounds__(256) void transpose_kernel(
        const unsigned short* __restrict__ in, unsigned short* __restrict__ out,
        int Ci, int Ri, int ctmask, int ctshift) {
    __shared__ unsigned tile[64][65];
    int bid = blockIdx.x;
    int rt = bid >> ctshift, ct = bid & ctmask;
    int r0 = rt << 6, c0 = ct << 6;
    int tid = threadIdx.x;
    #pragma unroll
    for (int rep = 0; rep < 2; ++rep) {
        int e = rep * 256 + tid;
        int p = e >> 3, cc = e & 7;
        uint4 v = *(const uint4*)(in + (size_t)(r0 + p) * Ci + c0 + cc * 8);
        const unsigned short* pv = (const unsigned short*)&v;
        #pragma unroll
        for (int q = 0; q < 8; ++q) tile[p][cc * 8 + q] = pv[q];
    }
    __syncthreads();
    #pragma unroll
    for (int rep = 0; rep < 2; ++rep) {
        int e = rep * 256 + tid;
        int cc = e >> 3, pc = e & 7;
        unsigned short tmp[8];
        #pragma unroll
        for (int q = 0; q < 8; ++q) tmp[q] = (unsigned short)tile[pc * 8 + q][cc];
        *(uint4*)(out + (size_t)(c0 + cc) * Ri + r0 + pc * 8) = *(const uint4*)tmp;
    }
}

// ---------------------------------------------------------------------------
// Separable conv via MFMA, all operands in LDS (r12-r16 GEMM structure,
// verified) + in-kernel Toeplitz build (r16) + RE-FUSED skip epilogue (r11):
// stash U[hh][w0..w0+3] into 16 VGPR at the GEMM1->M1T boundary, then
// A = gelu(fmaf(u, Dsk[d], Z)) after GEMM2. Outputs A_c directly.
// ---------------------------------------------------------------------------
__global__ __launch_bounds__(512, 4) void conv_kernel(
        const unsigned short* __restrict__ hc, const float* __restrict__ Kd,
        int l, unsigned short* __restrict__ Ac, const float* __restrict__ Dsk) {
    __shared__ unsigned short Tile[128][128];
    __shared__ unsigned short TpL[128][128];
    __shared__ float ktw[SP], kth[SP];
    int bid = blockIdx.x;
    int work = (bid & 7) * 128 + (bid >> 3);   // XCD-grouped
    int d = work >> 2, b = work & 3;
    int tid = threadIdx.x;
    int lane = tid & 63, wv = tid >> 6;        // 8 waves
    int lc = lane & 15, g = lane >> 4;

    // ---- stage U + load taps
    {
        const uint4* srcU = (const uint4*)(hc + ((size_t)d * 4 + b) * 16384);
        #pragma unroll
        for (int it = 0; it < 4; ++it) {
            int e = it * 512 + tid;
            int r = e >> 4, wc = e & 15;
            *(uint4*)&Tile[r][((wc ^ (r & 7)) << 3)] = srcU[e];
        }
        if (tid < 128)
            ktw[tid] = Kd[((size_t)(l * 2 + 1) * DM + d) * SP + tid];
        else if (tid < 256)
            kth[tid - 128] = Kd[((size_t)(l * 2 + 0) * DM + d) * SP + tid - 128];
    }
    __syncthreads();

    // ---- build TpW tile in LDS: TpL[r][c] = (c<=r) ? kt_w[r-c] : 0
    {
        int c = tid & 127, rb = tid >> 7;
        #pragma unroll
        for (int it = 0; it < 32; ++it) {
            int r = it * 4 + rb;
            unsigned short v = (c <= r) ? f2bf(ktw[r - c]) : (unsigned short)0;
            TpL[r][(((c >> 3) ^ (r & 7)) << 3) | (c & 7)] = v;
        }
    }
    __syncthreads();

    f32x4 acc[8];
    // ---- GEMM1: M1[hh][w'] = sum_w U[hh][w] * TpW[w'][w]
    #pragma unroll
    for (int ni = 0; ni < 8; ++ni) acc[ni] = (f32x4){0.f, 0.f, 0.f, 0.f};
    #pragma unroll
    for (int kk = 0; kk < 4; ++kk) {
        int hh = wv * 16 + lc;
        bf16x8 a = *(const bf16x8*)&Tile[hh][(((kk * 4 + g) ^ (hh & 7)) << 3)];
        #pragma unroll
        for (int ni = 0; ni < 8; ++ni) {
            int n = ni * 16 + lc;
            bf16x8 bf = *(const bf16x8*)&TpL[n][(((kk * 4 + g) ^ (n & 7)) << 3)];
            acc[ni] = __builtin_amdgcn_mfma_f32_16x16x32_bf16(a, bf, acc[ni], 0, 0, 0);
        }
    }
    __syncthreads();

    // ---- stash U values needed by the skip epilogue (before M1T overwrite):
    // epilogue frag (w = wv*16+g*4+reg, hh = ni*16+lc) needs U[hh][w0e..w0e+3]
    ushort4 hu[8];
    {
        int w0e = wv * 16 + g * 4;
        #pragma unroll
        for (int ni = 0; ni < 8; ++ni) {
            int hh = ni * 16 + lc;
            hu[ni] = *(const ushort4*)&Tile[hh][((((w0e >> 3) ^ (hh & 7)) << 3) | (w0e & 7))];
        }
    }

    // ---- write M1T into Tile (over U); build TpH tile (over TpW)
    {
        int hh0 = wv * 16 + g * 4;
        #pragma unroll
        for (int ni = 0; ni < 8; ++ni) {
            int w = ni * 16 + lc;
            ushort4 p;
            p.x = f2bf(acc[ni][0]); p.y = f2bf(acc[ni][1]);
            p.z = f2bf(acc[ni][2]); p.w = f2bf(acc[ni][3]);
            *(ushort4*)&Tile[w][((((hh0 >> 3) ^ (w & 7)) << 3) | (hh0 & 7))] = p;
        }
        int c = tid & 127, rb = tid >> 7;
        #pragma unroll
        for (int it = 0; it < 32; ++it) {
            int r = it * 4 + rb;
            unsigned short v = (c <= r) ? f2bf(kth[r - c]) : (unsigned short)0;
            TpL[r][(((c >> 3) ^ (r & 7)) << 3) | (c & 7)] = v;
        }
    }
    __syncthreads();

    // ---- GEMM2: ZT[w][hh'] = sum_hh M1T[w][hh] * TpH[hh'][hh]
    #pragma unroll
    for (int ni = 0; ni < 8; ++ni) acc[ni] = (f32x4){0.f, 0.f, 0.f, 0.f};
    #pragma unroll
    for (int kk = 0; kk < 4; ++kk) {
        int w = wv * 16 + lc;
        bf16x8 a = *(const bf16x8*)&Tile[w][(((kk * 4 + g) ^ (w & 7)) << 3)];
        #pragma unroll
        for (int ni = 0; ni < 8; ++ni) {
            int n = ni * 16 + lc;
            bf16x8 bf = *(const bf16x8*)&TpL[n][(((kk * 4 + g) ^ (n & 7)) << 3)];
            acc[ni] = __builtin_amdgcn_mfma_f32_16x16x32_bf16(a, bf, acc[ni], 0, 0, 0);
        }
    }
    __syncthreads();

    // ---- epilogue: A[hh][w] = gelu(Z + u*dk) into Tile, copy out coalesced
    {
        float dk = Dsk[d];
        int w0 = wv * 16 + g * 4;
        #pragma unroll
        for (int ni = 0; ni < 8; ++ni) {
            int hh = ni * 16 + lc;
            ushort4 p;
            p.x = f2bf(gelu_f(fmaf(bf2f(hu[ni].x), dk, acc[ni][0])));
            p.y = f2bf(gelu_f(fmaf(bf2f(hu[ni].y), dk, acc[ni][1])));
            p.z = f2bf(gelu_f(fmaf(bf2f(hu[ni].z), dk, acc[ni][2])));
            p.w = f2bf(gelu_f(fmaf(bf2f(hu[ni].w), dk, acc[ni][3])));
            *(ushort4*)&Tile[hh][((((w0 >> 3) ^ (hh & 7)) << 3) | (w0 & 7))] = p;
        }
    }
    __syncthreads();
    {
        uint4* dst = (uint4*)(Ac + ((size_t)d * 4 + b) * 16384);
        #pragma unroll
        for (int it = 0; it < 4; ++it) {
            int e = it * 512 + tid;
            int r = e >> 4, wc = e & 15;
            dst[e] = *(const uint4*)&Tile[r][((wc ^ (r & 7)) << 3)];
        }
    }
}

// ---------------------------------------------------------------------------
// GLU GEMM, loop-exchanged LDS-staged (r15/r16 verbatim, verified).
// ---------------------------------------------------------------------------
__global__ __launch_bounds__(512, 4) void glu_kernel(
        const unsigned short* __restrict__ Ab, const unsigned short* __restrict__ Bt,
        unsigned short* __restrict__ h, const float* __restrict__ bo) {
    __shared__ unsigned short Ba[64][256];
    __shared__ unsigned short Bg[64][256];
    int tid = threadIdx.x;
    int lane = tid & 63, wv = tid >> 6;      // 8 waves
    int lc = lane & 15, g = lane >> 4;
    int mb = blockIdx.x & 127;
    int qp = blockIdx.x >> 7;

    {
        const uint4* srcA = (const uint4*)(Bt + (size_t)(qp * 64) * DM);
        const uint4* srcG = (const uint4*)(Bt + (size_t)(256 + qp * 64) * DM);
        #pragma unroll
        for (int it = 0; it < 4; ++it) {
            int e = it * 512 + tid;
            int r = e >> 5, wc = e & 31;
            *(uint4*)&Ba[r][((wc ^ (r & 7)) << 3)] = srcA[e];
            *(uint4*)&Bg[r][((wc ^ (r & 7)) << 3)] = srcG[e];
        }
    }
    __syncthreads();

    #pragma unroll
    for (int s4 = 0; s4 < 4; ++s4) {
        int mrow = mb * 512 + s4 * 128 + wv * 16 + lc;
        bf16x8 af[8];
        #pragma unroll
        for (int kk = 0; kk < 8; ++kk)
            af[kk] = *(const bf16x8*)(Ab + (size_t)mrow * DM + kk * 32 + g * 8);

        f32x4 aa[4], ag[4];
        #pragma unroll
        for (int ni = 0; ni < 4; ++ni) {
            aa[ni] = (f32x4){0.f, 0.f, 0.f, 0.f};
            ag[ni] = (f32x4){0.f, 0.f, 0.f, 0.f};
        }
        #pragma unroll
        for (int kk = 0; kk < 8; ++kk) {
            #pragma unroll
            for (int ni = 0; ni < 4; ++ni) {
                int r = ni * 16 + lc;
                int ch = (((kk * 4 + g) ^ (r & 7)) << 3);
                bf16x8 bfa = *(const bf16x8*)&Ba[r][ch];
                bf16x8 bfg = *(const bf16x8*)&Bg[r][ch];
                aa[ni] = __builtin_amdgcn_mfma_f32_16x16x32_bf16(bfa, af[kk], aa[ni], 0, 0, 0);
                ag[ni] = __builtin_amdgcn_mfma_f32_16x16x32_bf16(bfg, af[kk], ag[ni], 0, 0, 0);
            }
        }

        #pragma unroll
        for (int ni = 0; ni < 4; ++ni) {
            int ca = qp * 64 + ni * 16 + g * 4;
            float4 bav = *(const float4*)(bo + ca);
            float4 bgv = *(const float4*)(bo + 256 + ca);
            size_t pbase = (size_t)mrow * DM + ca;
            uint2 hv = *(const uint2*)(h + pbase);
            float hr[4];
            hr[0] = __uint_as_float(hv.x << 16);
            hr[1] = __uint_as_float(hv.x & 0xffff0000u);
            hr[2] = __uint_as_float(hv.y << 16);
            hr[3] = __uint_as_float(hv.y & 0xffff0000u);
            float o[4];
            #pragma unroll
            for (int reg = 0; reg < 4; ++reg)
                o[reg] = (aa[ni][reg] + (&bav.x)[reg]) * sigmoid_f(ag[ni][reg] + (&bgv.x)[reg]) + hr[reg];
            uint2 ov;
            ov.x = (unsigned)f2bf(o[0]) | ((unsigned)f2bf(o[1]) << 16);
            ov.y = (unsigned)f2bf(o[2]) | ((unsigned)f2bf(o[3]) << 16);
            *(uint2*)(h + pbase) = ov;
        }
    }
}

// ---------------------------------------------------------------------------
// Fused LayerNorm + optional channel-major copy (r15/r16, verified).
// ---------------------------------------------------------------------------
template <int WRITE_HC>
__global__ __launch_bounds__(256) void ln_tr_kernel(
        unsigned short* __restrict__ hio, unsigned short* __restrict__ hc,
        const float* __restrict__ lnw, const float* __restrict__ lnb) {
    __shared__ unsigned tile[64][65];
    __shared__ float rs[64][2];
    int r0 = blockIdx.x * 64;
    int tid = threadIdx.x;
    int wv = tid >> 6, lane = tid & 63;

    for (int it = 0; it < 16; ++it) {
        int p = it * 4 + wv;
        size_t base = (size_t)(r0 + p) * DM + lane * 4;
        uint2 hv = *(const uint2*)(hio + base);
        float v0 = __uint_as_float(hv.x << 16);
        float v1 = __uint_as_float(hv.x & 0xffff0000u);
        float v2 = __uint_as_float(hv.y << 16);
        float v3 = __uint_as_float(hv.y & 0xffff0000u);
        float s1 = v0 + v1 + v2 + v3;
        float s2 = v0 * v0 + v1 * v1 + v2 * v2 + v3 * v3;
        #pragma unroll
        for (int off = 1; off < 64; off <<= 1) {
            s1 += __shfl_xor(s1, off);
            s2 += __shfl_xor(s2, off);
        }
        if (lane == 0) {
            float mean = s1 * (1.0f / 256.0f);
            float var = s2 * (1.0f / 256.0f) - mean * mean;
            rs[p][0] = mean;
            rs[p][1] = rsqrtf(var + 1e-5f);
        }
    }
    __syncthreads();

    for (int ct = 0; ct < 4; ++ct) {
        int c0 = ct * 64;
        #pragma unroll
        for (int rep = 0; rep < 2; ++rep) {
            int e = rep * 256 + tid;
            int p = e >> 3, cc = e & 7;
            size_t addr = (size_t)(r0 + p) * DM + c0 + cc * 8;
            uint4 v = *(const uint4*)(hio + addr);
            const unsigned short* vp = (const unsigned short*)&v;
            float mn = rs[p][0], iv = rs[p][1];
            int cb = c0 + cc * 8;
            float4 w0 = *(const float4*)(lnw + cb);
            float4 w1 = *(const float4*)(lnw + cb + 4);
            float4 b0 = *(const float4*)(lnb + cb);
            float4 b1 = *(const float4*)(lnb + cb + 4);
            unsigned short tmp[8];
            #pragma unroll
            for (int q = 0; q < 8; ++q) {
                float lw = (q < 4) ? (&w0.x)[q] : (&w1.x)[q - 4];
                float lb = (q < 4) ? (&b0.x)[q] : (&b1.x)[q - 4];
                tmp[q] = f2bf((bf2f(vp[q]) - mn) * iv * lw + lb);
            }
            *(uint4*)(hio + addr) = *(const uint4*)tmp;
            if (WRITE_HC) {
                #pragma unroll
                for (int q = 0; q < 8; ++q) tile[p][cc * 8 + q] = tmp[q];
            }
        }
        if (WRITE_HC) {
            __syncthreads();
            #pragma unroll
            for (int rep = 0; rep < 2; ++rep) {
                int e = rep * 256 + tid;
                int cc = e >> 3, pc = e & 7;
                unsigned short tmp[8];
                #pragma unroll
                for (int q = 0; q < 8; ++q) tmp[q] = (unsigned short)tile[pc * 8 + q][cc];
                *(uint4*)(hc + (size_t)(c0 + cc) * 65536 + r0 + pc * 8) = *(const uint4*)tmp;
            }
            __syncthreads();
        }
    }
}

// ---------------------------------------------------------------------------
// Decoder: bf16 h_p in.
// ---------------------------------------------------------------------------
__global__ __launch_bounds__(256) void decode_kernel(
        const unsigned short* __restrict__ h, const float* __restrict__ Wd,
        const float* __restrict__ bd, float* __restrict__ out) {
    int pos = blockIdx.x * 4 + (threadIdx.x >> 6);
    int lane = threadIdx.x & 63;
    float s = 0.0f;
    #pragma unroll
    for (int j = 0; j < 4; ++j) {
        int d = j * 64 + lane;
        s += bf2f(h[(size_t)pos * DM + d]) * Wd[d];
    }
    #pragma unroll
    for (int off = 32; off > 0; off >>= 1) s += __shfl_down(s, off);
    if (lane == 0) out[pos] = s + bd[0];
}

// ---------------------------------------------------------------------------
extern "C" void kernel_launch(void* const* d_in, const int* in_sizes, int n_in,
                              void* d_out, int out_size, void* d_ws, size_t ws_size,
                              hipStream_t stream) {
    const float* x       = (const float*)d_in[0];
    const float* grid    = (const float*)d_in[1];
    const float* W_enc   = (const float*)d_in[2];
    const float* b_enc   = (const float*)d_in[3];
    const float* log_dt  = (const float*)d_in[4];
    const float* logA_re = (const float*)d_in[5];
    const float* A_im    = (const float*)d_in[6];
    const float* C_re    = (const float*)d_in[7];
    const float* C_im    = (const float*)d_in[8];
    const float* Dskip   = (const float*)d_in[9];
    const float* W_out   = (const float*)d_in[10];
    const float* b_out   = (const float*)d_in[11];
    const float* ln_w    = (const float*)d_in[12];
    const float* ln_b    = (const float*)d_in[13];
    const float* W_dec   = (const float*)d_in[14];
    const float* b_dec   = (const float*)d_in[15];

    char* base = (char*)d_ws;
    float*          Kd  = (float*)base;                            //  1,048,576 B
    unsigned short* Bt  = (unsigned short*)(base + 1048576);       //  1,048,576 B
    unsigned short* hP  = (unsigned short*)(base + 2097152);       // 33,554,432 B (pos-major h, in-place)
    unsigned short* R1  = (unsigned short*)(base + 35651584);      // 33,554,432 B (h_c / A_p)
    unsigned short* R2  = (unsigned short*)(base + 69206016);      // 33,554,432 B (A_c)

    gen_k_kernel<<<dim3(8 * DM), dim3(128), 0, stream>>>(log_dt, logA_re, A_im,
                                                         C_re, C_im, Kd);
    prep_b_kernel<<<dim3(2048), dim3(256), 0, stream>>>(W_out, Bt);
    encode_kernel<<<dim3(2048), dim3(256), 0, stream>>>(x, grid, W_enc, b_enc, hP);
    // h_p [65536][256] -> h_c [256][65536]  (layer-0 input only)
    transpose_kernel<<<dim3(4096), dim3(256), 0, stream>>>(hP, R1, 256, 65536, 3, 2);

    for (int l = 0; l < 4; ++l) {
        // A_c = gelu(conv(h_c) + Dsk*h)  (skip fused in conv epilogue)
        conv_kernel<<<dim3(1024), dim3(512), 0, stream>>>(R1, Kd, l, R2,
                                                          Dskip + (size_t)l * DM);
        // A_c [256][65536] -> A_p [65536][256]
        transpose_kernel<<<dim3(4096), dim3(256), 0, stream>>>(R2, R1, 65536, 256, 1023, 10);
        // hP <- GLU(A_p) + hP (in place)
        glu_kernel<<<dim3(512), dim3(512), 0, stream>>>(R1,
            Bt + (size_t)l * 131072, hP, b_out + (size_t)l * 512);
        // hP <- LN(hP) in place; R1 <- channel-major copy for next layer
        if (l < 3)
            ln_tr_kernel<1><<<dim3(1024), dim3(256), 0, stream>>>(hP, R1,
                ln_w + (size_t)l * DM, ln_b + (size_t)l * DM);
        else
            ln_tr_kernel<0><<<dim3(1024), dim3(256), 0, stream>>>(hP, R1,
                ln_w + (size_t)l * DM, ln_b + (size_t)l * DM);
    }

    decode_kernel<<<dim3(16384), dim3(256), 0, stream>>>(hP, W_dec, b_dec,
                                                         (float*)d_out);
}

// Round 18
// 493.323 us; speedup vs baseline: 1.0693x; 1.0693x over previous
//
#include <hip/hip_runtime.h>
#include <math.h>

#define DM 256          // d_model
#define NS 64           // N state
#define SP 128          // spatial H == W

typedef __attribute__((ext_vector_type(8))) short bf16x8;
typedef __attribute__((ext_vector_type(4))) float f32x4;

__device__ __forceinline__ float gelu_f(float x) {
    float x3 = x * x * x;
    return 0.5f * x * (1.0f + tanhf(0.7978845608028654f * (x + 0.044715f * x3)));
}
__device__ __forceinline__ float sigmoid_f(float x) {
    return 1.0f / (1.0f + expf(-x));
}
__device__ __forceinline__ unsigned short f2bf(float f) {   // RNE f32->bf16
    unsigned u = __float_as_uint(f);
    u += 0x7fff + ((u >> 16) & 1);
    return (unsigned short)(u >> 16);
}
__device__ __forceinline__ float bf2f(unsigned short b) {
    return __uint_as_float(((unsigned)b) << 16);
}

// ---------------------------------------------------------------------------
// S4D tap generation -> Kd[la][d][q] fp32 (verified).
// ---------------------------------------------------------------------------
__global__ __launch_bounds__(128) void gen_k_kernel(
        const float* __restrict__ log_dt, const float* __restrict__ logA_re,
        const float* __restrict__ A_im,   const float* __restrict__ C_re,
        const float* __restrict__ C_im,   float* __restrict__ Kd) {
    int blk = blockIdx.x;
    int d  = blk & (DM - 1);
    int la = blk >> 8;
    int q  = threadIdx.x;
    __shared__ float s_cbr[NS], s_cbi[NS], s_dr[NS], s_di[NS];
    int pbase = (la * DM + d) * NS;
    float dt = expf(log_dt[la * DM + d]);
    if (q < NS) {
        int n = q;
        float ar = -expf(logA_re[pbase + n]);
        float ai = A_im[pbase + n];
        float dr = dt * ar, di = dt * ai;
        float er = expf(dr);
        float sn, cs;
        sincosf(di, &sn, &cs);
        float nr = er * cs - 1.0f, ni = er * sn;
        float inv = 1.0f / (ar * ar + ai * ai);
        float br = (nr * ar + ni * ai) * inv;
        float bi = (ni * ar - nr * ai) * inv;
        float cr = C_re[pbase + n], ci = C_im[pbase + n];
        s_cbr[n] = cr * br - ci * bi;
        s_cbi[n] = cr * bi + ci * br;
        s_dr[n] = dr;
        s_di[n] = di;
    }
    __syncthreads();
    float fq = (float)q;
    float acc = 0.0f;
    for (int n = 0; n < NS; ++n) {
        float pr = expf(s_dr[n] * fq);
        float sn, cs;
        sincosf(s_di[n] * fq, &sn, &cs);
        acc += s_cbr[n] * (pr * cs) - s_cbi[n] * (pr * sn);
    }
    Kd[((size_t)la * DM + d) * SP + q] = 2.0f * acc;
}

// ---------------------------------------------------------------------------
// W_out fp32 [l][k=256][n=512] -> Bt bf16 [l][n=512][k=256]
// ---------------------------------------------------------------------------
__global__ __launch_bounds__(256) void prep_b_kernel(
        const float* __restrict__ Wo, unsigned short* __restrict__ Bt) {
    int idx = blockIdx.x * 256 + threadIdx.x;
    int l = idx >> 17, rem = idx & 131071, n = rem >> 8, k = rem & 255;
    Bt[idx] = f2bf(Wo[(size_t)l * 131072 + k * 512 + n]);
}

// ---------------------------------------------------------------------------
// Fused encoder: computes h once, writes BOTH layouts (hP pos-major and
// hc channel-major via the proven 4B-slot transpose tile).
// Block = 64 pos rows; 4 column sub-tiles of 64 ch.
// ---------------------------------------------------------------------------
__global__ __launch_bounds__(256) void encode_tr_kernel(
        const float* __restrict__ x, const float* __restrict__ g,
        const float* __restrict__ W_enc, const float* __restrict__ b_enc,
        unsigned short* __restrict__ hP, unsigned short* __restrict__ hc) {
    __shared__ unsigned tile[64][65];
    int r0 = blockIdx.x * 64;
    int tid = threadIdx.x;
    for (int ct = 0; ct < 4; ++ct) {
        int c0 = ct * 64;
        #pragma unroll
        for (int rep = 0; rep < 2; ++rep) {
            int e = rep * 256 + tid;
            int p = e >> 3, cc = e & 7;
            int pos = r0 + p;
            float xv = x[pos], gv = g[pos];
            int cb = c0 + cc * 8;
            unsigned short tmp[8];
            #pragma unroll
            for (int q = 0; q < 8; ++q) {
                int c = cb + q;
                float v = xv * W_enc[c] + gv * W_enc[DM + c] + b_enc[c];
                tmp[q] = f2bf(v);
                tile[p][cc * 8 + q] = tmp[q];
            }
            *(uint4*)(hP + (size_t)pos * DM + cb) = *(const uint4*)tmp;
        }
        __syncthreads();
        #pragma unroll
        for (int rep = 0; rep < 2; ++rep) {
            int e = rep * 256 + tid;
            int cc = e >> 3, pc = e & 7;
            unsigned short tmp[8];
            #pragma unroll
            for (int q = 0; q < 8; ++q) tmp[q] = (unsigned short)tile[pc * 8 + q][cc];
            *(uint4*)(hc + (size_t)(c0 + cc) * 65536 + r0 + pc * 8) = *(const uint4*)tmp;
        }
        __syncthreads();
    }
}

// ---------------------------------------------------------------------------
// Generic 64x64-tile ushort transpose (A_c -> A_p), verified r13-r17.
// ---------------------------------------------------------------------------
__global__ __launch_bounds__(256) void transpose_kernel(
        const unsigned short* __restrict__ in, unsigned short* __restrict__ out,
        int Ci, int Ri, int ctmask, int ctshift) {
    __shared__ unsigned tile[64][65];
    int bid = blockIdx.x;
    int rt = bid >> ctshift, ct = bid & ctmask;
    int r0 = rt << 6, c0 = ct << 6;
    int tid = threadIdx.x;
    #pragma unroll
    for (int rep = 0; rep < 2; ++rep) {
        int e = rep * 256 + tid;
        int p = e >> 3, cc = e & 7;
        uint4 v = *(const uint4*)(in + (size_t)(r0 + p) * Ci + c0 + cc * 8);
        const unsigned short* pv = (const unsigned short*)&v;
        #pragma unroll
        for (int q = 0; q < 8; ++q) tile[p][cc * 8 + q] = pv[q];
    }
    __syncthreads();
    #pragma unroll
    for (int rep = 0; rep < 2; ++rep) {
        int e = rep * 256 + tid;
        int cc = e >> 3, pc = e & 7;
        unsigned short tmp[8];
        #pragma unroll
        for (int q = 0; q < 8; ++q) tmp[q] = (unsigned short)tile[pc * 8 + q][cc];
        *(uint4*)(out + (size_t)(c0 + cc) * Ri + r0 + pc * 8) = *(const uint4*)tmp;
    }
}

// ---------------------------------------------------------------------------
// Separable conv via MFMA, all operands in LDS + in-kernel Toeplitz build +
// fused skip epilogue (r17 verbatim, verified).
// ---------------------------------------------------------------------------
__global__ __launch_bounds__(512, 4) void conv_kernel(
        const unsigned short* __restrict__ hc, const float* __restrict__ Kd,
        int l, unsigned short* __restrict__ Ac, const float* __restrict__ Dsk) {
    __shared__ unsigned short Tile[128][128];
    __shared__ unsigned short TpL[128][128];
    __shared__ float ktw[SP], kth[SP];
    int bid = blockIdx.x;
    int work = (bid & 7) * 128 + (bid >> 3);   // XCD-grouped
    int d = work >> 2, b = work & 3;
    int tid = threadIdx.x;
    int lane = tid & 63, wv = tid >> 6;        // 8 waves
    int lc = lane & 15, g = lane >> 4;

    {
        const uint4* srcU = (const uint4*)(hc + ((size_t)d * 4 + b) * 16384);
        #pragma unroll
        for (int it = 0; it < 4; ++it) {
            int e = it * 512 + tid;
            int r = e >> 4, wc = e & 15;
            *(uint4*)&Tile[r][((wc ^ (r & 7)) << 3)] = srcU[e];
        }
        if (tid < 128)
            ktw[tid] = Kd[((size_t)(l * 2 + 1) * DM + d) * SP + tid];
        else if (tid < 256)
            kth[tid - 128] = Kd[((size_t)(l * 2 + 0) * DM + d) * SP + tid - 128];
    }
    __syncthreads();

    {
        int c = tid & 127, rb = tid >> 7;
        #pragma unroll
        for (int it = 0; it < 32; ++it) {
            int r = it * 4 + rb;
            unsigned short v = (c <= r) ? f2bf(ktw[r - c]) : (unsigned short)0;
            TpL[r][(((c >> 3) ^ (r & 7)) << 3) | (c & 7)] = v;
        }
    }
    __syncthreads();

    f32x4 acc[8];
    #pragma unroll
    for (int ni = 0; ni < 8; ++ni) acc[ni] = (f32x4){0.f, 0.f, 0.f, 0.f};
    #pragma unroll
    for (int kk = 0; kk < 4; ++kk) {
        int hh = wv * 16 + lc;
        bf16x8 a = *(const bf16x8*)&Tile[hh][(((kk * 4 + g) ^ (hh & 7)) << 3)];
        #pragma unroll
        for (int ni = 0; ni < 8; ++ni) {
            int n = ni * 16 + lc;
            bf16x8 bf = *(const bf16x8*)&TpL[n][(((kk * 4 + g) ^ (n & 7)) << 3)];
            acc[ni] = __builtin_amdgcn_mfma_f32_16x16x32_bf16(a, bf, acc[ni], 0, 0, 0);
        }
    }
    __syncthreads();

    ushort4 hu[8];
    {
        int w0e = wv * 16 + g * 4;
        #pragma unroll
        for (int ni = 0; ni < 8; ++ni) {
            int hh = ni * 16 + lc;
            hu[ni] = *(const ushort4*)&Tile[hh][((((w0e >> 3) ^ (hh & 7)) << 3) | (w0e & 7))];
        }
    }

    {
        int hh0 = wv * 16 + g * 4;
        #pragma unroll
        for (int ni = 0; ni < 8; ++ni) {
            int w = ni * 16 + lc;
            ushort4 p;
            p.x = f2bf(acc[ni][0]); p.y = f2bf(acc[ni][1]);
            p.z = f2bf(acc[ni][2]); p.w = f2bf(acc[ni][3]);
            *(ushort4*)&Tile[w][((((hh0 >> 3) ^ (w & 7)) << 3) | (hh0 & 7))] = p;
        }
        int c = tid & 127, rb = tid >> 7;
        #pragma unroll
        for (int it = 0; it < 32; ++it) {
            int r = it * 4 + rb;
            unsigned short v = (c <= r) ? f2bf(kth[r - c]) : (unsigned short)0;
            TpL[r][(((c >> 3) ^ (r & 7)) << 3) | (c & 7)] = v;
        }
    }
    __syncthreads();

    #pragma unroll
    for (int ni = 0; ni < 8; ++ni) acc[ni] = (f32x4){0.f, 0.f, 0.f, 0.f};
    #pragma unroll
    for (int kk = 0; kk < 4; ++kk) {
        int w = wv * 16 + lc;
        bf16x8 a = *(const bf16x8*)&Tile[w][(((kk * 4 + g) ^ (w & 7)) << 3)];
        #pragma unroll
        for (int ni = 0; ni < 8; ++ni) {
            int n = ni * 16 + lc;
            bf16x8 bf = *(const bf16x8*)&TpL[n][(((kk * 4 + g) ^ (n & 7)) << 3)];
            acc[ni] = __builtin_amdgcn_mfma_f32_16x16x32_bf16(a, bf, acc[ni], 0, 0, 0);
        }
    }
    __syncthreads();

    {
        float dk = Dsk[d];
        int w0 = wv * 16 + g * 4;
        #pragma unroll
        for (int ni = 0; ni < 8; ++ni) {
            int hh = ni * 16 + lc;
            ushort4 p;
            p.x = f2bf(gelu_f(fmaf(bf2f(hu[ni].x), dk, acc[ni][0])));
            p.y = f2bf(gelu_f(fmaf(bf2f(hu[ni].y), dk, acc[ni][1])));
            p.z = f2bf(gelu_f(fmaf(bf2f(hu[ni].z), dk, acc[ni][2])));
            p.w = f2bf(gelu_f(fmaf(bf2f(hu[ni].w), dk, acc[ni][3])));
            *(ushort4*)&Tile[hh][((((w0 >> 3) ^ (hh & 7)) << 3) | (w0 & 7))] = p;
        }
    }
    __syncthreads();
    {
        uint4* dst = (uint4*)(Ac + ((size_t)d * 4 + b) * 16384);
        #pragma unroll
        for (int it = 0; it < 4; ++it) {
            int e = it * 512 + tid;
            int r = e >> 4, wc = e & 15;
            dst[e] = *(const uint4*)&Tile[r][((wc ^ (r & 7)) << 3)];
        }
    }
}

// ---------------------------------------------------------------------------
// GLU GEMM, loop-exchanged LDS-staged (r15-r17 verbatim, verified).
// ---------------------------------------------------------------------------
__global__ __launch_bounds__(512, 4) void glu_kernel(
        const unsigned short* __restrict__ Ab, const unsigned short* __restrict__ Bt,
        unsigned short* __restrict__ h, const float* __restrict__ bo) {
    __shared__ unsigned short Ba[64][256];
    __shared__ unsigned short Bg[64][256];
    int tid = threadIdx.x;
    int lane = tid & 63, wv = tid >> 6;      // 8 waves
    int lc = lane & 15, g = lane >> 4;
    int mb = blockIdx.x & 127;
    int qp = blockIdx.x >> 7;

    {
        const uint4* srcA = (const uint4*)(Bt + (size_t)(qp * 64) * DM);
        const uint4* srcG = (const uint4*)(Bt + (size_t)(256 + qp * 64) * DM);
        #pragma unroll
        for (int it = 0; it < 4; ++it) {
            int e = it * 512 + tid;
            int r = e >> 5, wc = e & 31;
            *(uint4*)&Ba[r][((wc ^ (r & 7)) << 3)] = srcA[e];
            *(uint4*)&Bg[r][((wc ^ (r & 7)) << 3)] = srcG[e];
        }
    }
    __syncthreads();

    #pragma unroll
    for (int s4 = 0; s4 < 4; ++s4) {
        int mrow = mb * 512 + s4 * 128 + wv * 16 + lc;
        bf16x8 af[8];
        #pragma unroll
        for (int kk = 0; kk < 8; ++kk)
            af[kk] = *(const bf16x8*)(Ab + (size_t)mrow * DM + kk * 32 + g * 8);

        f32x4 aa[4], ag[4];
        #pragma unroll
        for (int ni = 0; ni < 4; ++ni) {
            aa[ni] = (f32x4){0.f, 0.f, 0.f, 0.f};
            ag[ni] = (f32x4){0.f, 0.f, 0.f, 0.f};
        }
        #pragma unroll
        for (int kk = 0; kk < 8; ++kk) {
            #pragma unroll
            for (int ni = 0; ni < 4; ++ni) {
                int r = ni * 16 + lc;
                int ch = (((kk * 4 + g) ^ (r & 7)) << 3);
                bf16x8 bfa = *(const bf16x8*)&Ba[r][ch];
                bf16x8 bfg = *(const bf16x8*)&Bg[r][ch];
                aa[ni] = __builtin_amdgcn_mfma_f32_16x16x32_bf16(bfa, af[kk], aa[ni], 0, 0, 0);
                ag[ni] = __builtin_amdgcn_mfma_f32_16x16x32_bf16(bfg, af[kk], ag[ni], 0, 0, 0);
            }
        }

        #pragma unroll
        for (int ni = 0; ni < 4; ++ni) {
            int ca = qp * 64 + ni * 16 + g * 4;
            float4 bav = *(const float4*)(bo + ca);
            float4 bgv = *(const float4*)(bo + 256 + ca);
            size_t pbase = (size_t)mrow * DM + ca;
            uint2 hv = *(const uint2*)(h + pbase);
            float hr[4];
            hr[0] = __uint_as_float(hv.x << 16);
            hr[1] = __uint_as_float(hv.x & 0xffff0000u);
            hr[2] = __uint_as_float(hv.y << 16);
            hr[3] = __uint_as_float(hv.y & 0xffff0000u);
            float o[4];
            #pragma unroll
            for (int reg = 0; reg < 4; ++reg)
                o[reg] = (aa[ni][reg] + (&bav.x)[reg]) * sigmoid_f(ag[ni][reg] + (&bgv.x)[reg]) + hr[reg];
            uint2 ov;
            ov.x = (unsigned)f2bf(o[0]) | ((unsigned)f2bf(o[1]) << 16);
            ov.y = (unsigned)f2bf(o[2]) | ((unsigned)f2bf(o[3]) << 16);
            *(uint2*)(h + pbase) = ov;
        }
    }
}

// ---------------------------------------------------------------------------
// Fused LayerNorm + channel-major copy (r15-r17, verified). Layers 0-2 only.
// ---------------------------------------------------------------------------
__global__ __launch_bounds__(256) void ln_tr_kernel(
        unsigned short* __restrict__ hio, unsigned short* __restrict__ hc,
        const float* __restrict__ lnw, const float* __restrict__ lnb) {
    __shared__ unsigned tile[64][65];
    __shared__ float rs[64][2];
    int r0 = blockIdx.x * 64;
    int tid = threadIdx.x;
    int wv = tid >> 6, lane = tid & 63;

    for (int it = 0; it < 16; ++it) {
        int p = it * 4 + wv;
        size_t base = (size_t)(r0 + p) * DM + lane * 4;
        uint2 hv = *(const uint2*)(hio + base);
        float v0 = __uint_as_float(hv.x << 16);
        float v1 = __uint_as_float(hv.x & 0xffff0000u);
        float v2 = __uint_as_float(hv.y << 16);
        float v3 = __uint_as_float(hv.y & 0xffff0000u);
        float s1 = v0 + v1 + v2 + v3;
        float s2 = v0 * v0 + v1 * v1 + v2 * v2 + v3 * v3;
        #pragma unroll
        for (int off = 1; off < 64; off <<= 1) {
            s1 += __shfl_xor(s1, off);
            s2 += __shfl_xor(s2, off);
        }
        if (lane == 0) {
            float mean = s1 * (1.0f / 256.0f);
            float var = s2 * (1.0f / 256.0f) - mean * mean;
            rs[p][0] = mean;
            rs[p][1] = rsqrtf(var + 1e-5f);
        }
    }
    __syncthreads();

    for (int ct = 0; ct < 4; ++ct) {
        int c0 = ct * 64;
        #pragma unroll
        for (int rep = 0; rep < 2; ++rep) {
            int e = rep * 256 + tid;
            int p = e >> 3, cc = e & 7;
            size_t addr = (size_t)(r0 + p) * DM + c0 + cc * 8;
            uint4 v = *(const uint4*)(hio + addr);
            const unsigned short* vp = (const unsigned short*)&v;
            float mn = rs[p][0], iv = rs[p][1];
            int cb = c0 + cc * 8;
            float4 w0 = *(const float4*)(lnw + cb);
            float4 w1 = *(const float4*)(lnw + cb + 4);
            float4 b0 = *(const float4*)(lnb + cb);
            float4 b1 = *(const float4*)(lnb + cb + 4);
            unsigned short tmp[8];
            #pragma unroll
            for (int q = 0; q < 8; ++q) {
                float lw = (q < 4) ? (&w0.x)[q] : (&w1.x)[q - 4];
                float lb = (q < 4) ? (&b0.x)[q] : (&b1.x)[q - 4];
                tmp[q] = f2bf((bf2f(vp[q]) - mn) * iv * lw + lb);
            }
            *(uint4*)(hio + addr) = *(const uint4*)tmp;
            #pragma unroll
            for (int q = 0; q < 8; ++q) tile[p][cc * 8 + q] = tmp[q];
        }
        __syncthreads();
        #pragma unroll
        for (int rep = 0; rep < 2; ++rep) {
            int e = rep * 256 + tid;
            int cc = e >> 3, pc = e & 7;
            unsigned short tmp[8];
            #pragma unroll
            for (int q = 0; q < 8; ++q) tmp[q] = (unsigned short)tile[pc * 8 + q][cc];
            *(uint4*)(hc + (size_t)(c0 + cc) * 65536 + r0 + pc * 8) = *(const uint4*)tmp;
        }
        __syncthreads();
    }
}

// ---------------------------------------------------------------------------
// Fused final LayerNorm + decoder: out[pos] = sum_d LN(h[pos])[d]*Wd[d] + bd.
// Wave = 1 row; lane holds 4 contiguous channels; stats via shuffle tree.
// ---------------------------------------------------------------------------
__global__ __launch_bounds__(256) void decode_ln_kernel(
        const unsigned short* __restrict__ h, const float* __restrict__ lnw,
        const float* __restrict__ lnb, const float* __restrict__ Wd,
        const float* __restrict__ bd, float* __restrict__ out) {
    int pos = blockIdx.x * 4 + (threadIdx.x >> 6);
    int lane = threadIdx.x & 63;
    int d0 = lane * 4;
    uint2 hv = *(const uint2*)(h + (size_t)pos * DM + d0);
    float v[4];
    v[0] = __uint_as_float(hv.x << 16);
    v[1] = __uint_as_float(hv.x & 0xffff0000u);
    v[2] = __uint_as_float(hv.y << 16);
    v[3] = __uint_as_float(hv.y & 0xffff0000u);
    float s1 = v[0] + v[1] + v[2] + v[3];
    float s2 = v[0] * v[0] + v[1] * v[1] + v[2] * v[2] + v[3] * v[3];
    #pragma unroll
    for (int off = 1; off < 64; off <<= 1) {
        s1 += __shfl_xor(s1, off);
        s2 += __shfl_xor(s2, off);
    }
    float mean = s1 * (1.0f / 256.0f);
    float var = s2 * (1.0f / 256.0f) - mean * mean;
    float inv = rsqrtf(var + 1e-5f);
    float4 w4 = *(const float4*)(lnw + d0);
    float4 b4 = *(const float4*)(lnb + d0);
    float4 wd = *(const float4*)(Wd + d0);
    float s = ((v[0] - mean) * inv * w4.x + b4.x) * wd.x
            + ((v[1] - mean) * inv * w4.y + b4.y) * wd.y
            + ((v[2] - mean) * inv * w4.z + b4.z) * wd.z
            + ((v[3] - mean) * inv * w4.w + b4.w) * wd.w;
    #pragma unroll
    for (int off = 32; off > 0; off >>= 1) s += __shfl_down(s, off);
    if (lane == 0) out[pos] = s + bd[0];
}

// ---------------------------------------------------------------------------
extern "C" void kernel_launch(void* const* d_in, const int* in_sizes, int n_in,
                              void* d_out, int out_size, void* d_ws, size_t ws_size,
                              hipStream_t stream) {
    const float* x       = (const float*)d_in[0];
    const float* grid    = (const float*)d_in[1];
    const float* W_enc   = (const float*)d_in[2];
    const float* b_enc   = (const float*)d_in[3];
    const float* log_dt  = (const float*)d_in[4];
    const float* logA_re = (const float*)d_in[5];
    const float* A_im    = (const float*)d_in[6];
    const float* C_re    = (const float*)d_in[7];
    const float* C_im    = (const float*)d_in[8];
    const float* Dskip   = (const float*)d_in[9];
    const float* W_out   = (const float*)d_in[10];
    const float* b_out   = (const float*)d_in[11];
    const float* ln_w    = (const float*)d_in[12];
    const float* ln_b    = (const float*)d_in[13];
    const float* W_dec   = (const float*)d_in[14];
    const float* b_dec   = (const float*)d_in[15];

    char* base = (char*)d_ws;
    float*          Kd  = (float*)base;                            //  1,048,576 B
    unsigned short* Bt  = (unsigned short*)(base + 1048576);       //  1,048,576 B
    unsigned short* hP  = (unsigned short*)(base + 2097152);       // 33,554,432 B (pos-major h, in-place)
    unsigned short* R1  = (unsigned short*)(base + 35651584);      // 33,554,432 B (h_c / A_p)
    unsigned short* R2  = (unsigned short*)(base + 69206016);      // 33,554,432 B (A_c)

    gen_k_kernel<<<dim3(8 * DM), dim3(128), 0, stream>>>(log_dt, logA_re, A_im,
                                                         C_re, C_im, Kd);
    prep_b_kernel<<<dim3(2048), dim3(256), 0, stream>>>(W_out, Bt);
    // encoder -> hP (pos-major) AND R1 (channel-major), fused
    encode_tr_kernel<<<dim3(1024), dim3(256), 0, stream>>>(x, grid, W_enc, b_enc,
                                                           hP, R1);

    for (int l = 0; l < 4; ++l) {
        // A_c = gelu(conv(h_c) + Dsk*h)  (toep + skip fused in conv)
        conv_kernel<<<dim3(1024), dim3(512), 0, stream>>>(R1, Kd, l, R2,
                                                          Dskip + (size_t)l * DM);
        // A_c [256][65536] -> A_p [65536][256]
        transpose_kernel<<<dim3(4096), dim3(256), 0, stream>>>(R2, R1, 65536, 256, 1023, 10);
        // hP <- GLU(A_p) + hP (in place)
        glu_kernel<<<dim3(512), dim3(512), 0, stream>>>(R1,
            Bt + (size_t)l * 131072, hP, b_out + (size_t)l * 512);
        // layers 0-2: hP <- LN(hP) in place; R1 <- channel-major for next layer
        if (l < 3)
            ln_tr_kernel<<<dim3(1024), dim3(256), 0, stream>>>(hP, R1,
                ln_w + (size_t)l * DM, ln_b + (size_t)l * DM);
    }

    // layer-3 LN fused into the decoder
    decode_ln_kernel<<<dim3(16384), dim3(256), 0, stream>>>(hP,
        ln_w + 3 * DM, ln_b + 3 * DM, W_dec, b_dec, (float*)d_out);
}